// Round 1
// baseline (117.242 us; speedup 1.0000x reference)
//
#include <hip/hip_runtime.h>

// m_ij = MLP([dist, dist^-3]) is a scalar function of s = |r|^2 + eps^2 only.
// Tabulate it (float-exponent/mantissa-indexed table, 8 mantissa bits x 22
// octaves, s in [2^-14, 2^8]), then do symmetric all-pairs accumulation:
// acc[i] = sum_j m(s_ij) * (p_j - p_i)   (j==i contributes exactly 0).

#define EPS2      1.0e-4f
#define TAB_BITS  8
#define TAB_SHIFT (23 - TAB_BITS)            // 15
#define TAB_EMIN  113                        // biased exponent of 2^-14
#define TAB_BASE  (TAB_EMIN << TAB_BITS)     // 28928
#define TAB_OCT   22                         // 2^-14 .. 2^8
#define TAB_N     (TAB_OCT << TAB_BITS)      // 5632 intervals, 5633 values

#define NPART   2048
#define BLOCK   512
#define CHUNK   512                          // i-particles per block
#define NSPLIT  64                           // j-range splits
#define JPT     (NPART / NSPLIT)             // 32 j per thread

// ---------------- table build: one value per sample point ------------------
// 4 threads cooperate per entry (16 output-channels each), shfl-reduce.
__global__ void build_table(const float* __restrict__ W1, const float* __restrict__ b1,
                            const float* __restrict__ W2, const float* __restrict__ b2,
                            const float* __restrict__ W3, const float* __restrict__ b3,
                            float* __restrict__ tab) {
    int t = blockIdx.x * blockDim.x + threadIdx.x;
    int entry = t >> 2;
    int og = t & 3;
    if (entry > TAB_N) return;

    unsigned u = (unsigned)(entry + TAB_BASE) << TAB_SHIFT;
    float s = __uint_as_float(u);            // exact sample point
    float d = sqrtf(s);
    float idc = 1.0f / (s * d);

    float h1[64];
#pragma unroll
    for (int k = 0; k < 64; ++k) {
        float v = fmaf(d, W1[k], fmaf(idc, W1[64 + k], b1[k]));
        h1[k] = v > 0.0f ? v : 0.0f;
    }

    float part = 0.0f;
#pragma unroll 2
    for (int oo = 0; oo < 16; ++oo) {
        int o = og * 16 + oo;
        float acc = b2[o];
#pragma unroll
        for (int k = 0; k < 64; ++k)
            acc = fmaf(h1[k], W2[k * 64 + o], acc);
        acc = acc > 0.0f ? acc : 0.0f;
        part = fmaf(acc, W3[o], part);
    }
    part += __shfl_down(part, 2, 4);
    part += __shfl_down(part, 1, 4);
    if (og == 0) tab[entry] = part + b3[0];
}

// ---------------- all-pairs force accumulation -----------------------------
__global__ __launch_bounds__(BLOCK, 4)
void forces(const float* __restrict__ pos, const float* __restrict__ tab,
            float* __restrict__ out) {
    __shared__ float  tabs[TAB_N + 4];       // 22544 B
    __shared__ float4 ps[NPART];             // 32768 B

    const int split = blockIdx.x;
    const int chunk = blockIdx.y;
    const int b     = blockIdx.z;

    const float* posb = pos + (size_t)b * NPART * 3;
    for (int k = threadIdx.x; k <= TAB_N; k += BLOCK) tabs[k] = tab[k];
    for (int k = threadIdx.x; k < NPART; k += BLOCK)
        ps[k] = make_float4(posb[k * 3], posb[k * 3 + 1], posb[k * 3 + 2], 0.0f);
    __syncthreads();

    const int i = chunk * CHUNK + threadIdx.x;
    const float4 pi = ps[i];
    float ax = 0.0f, ay = 0.0f, az = 0.0f;

    const int j0 = split * JPT;
#pragma unroll 4
    for (int jj = 0; jj < JPT; ++jj) {
        float4 pj = ps[j0 + jj];             // wave-uniform -> LDS broadcast
        float dx = pj.x - pi.x;
        float dy = pj.y - pi.y;
        float dz = pj.z - pi.z;
        float s = fmaf(dx, dx, fmaf(dy, dy, fmaf(dz, dz, EPS2)));
        unsigned u = __float_as_uint(s);
        int idx = (int)(u >> TAB_SHIFT) - TAB_BASE;
        idx = idx < 0 ? 0 : (idx > TAB_N - 1 ? TAB_N - 1 : idx);
        float frac = (float)(u & ((1u << TAB_SHIFT) - 1)) * (1.0f / 32768.0f);
        float t0 = tabs[idx];
        float t1 = tabs[idx + 1];
        float m = fmaf(frac, t1 - t0, t0);
        ax = fmaf(m, dx, ax);
        ay = fmaf(m, dy, ay);
        az = fmaf(m, dz, az);
    }

    float* o = out + ((size_t)b * NPART + i) * 3;
    atomicAdd(o + 0, ax);
    atomicAdd(o + 1, ay);
    atomicAdd(o + 2, az);
}

extern "C" void kernel_launch(void* const* d_in, const int* in_sizes, int n_in,
                              void* d_out, int out_size, void* d_ws, size_t ws_size,
                              hipStream_t stream) {
    const float* pos = (const float*)d_in[0];
    const float* W1  = (const float*)d_in[1];
    const float* b1  = (const float*)d_in[2];
    const float* W2  = (const float*)d_in[3];
    const float* b2  = (const float*)d_in[4];
    const float* W3  = (const float*)d_in[5];
    const float* b3  = (const float*)d_in[6];
    float* out = (float*)d_out;
    float* tab = (float*)d_ws;               // (TAB_N+1) floats = 22.5 KB

    const int B = in_sizes[0] / (NPART * 3); // = 2

    hipMemsetAsync(d_out, 0, (size_t)out_size * sizeof(float), stream);

    int build_threads = (TAB_N + 1) * 4;
    build_table<<<(build_threads + 255) / 256, 256, 0, stream>>>(W1, b1, W2, b2, W3, b3, tab);

    forces<<<dim3(NSPLIT, NPART / CHUNK, B), BLOCK, 0, stream>>>(pos, tab, out);
}

// Round 2
// 111.481 us; speedup vs baseline: 1.0517x; 1.0517x over previous
//
#include <hip/hip_runtime.h>

// m_ij = MLP([dist, dist^-3]) is a scalar function of s = |r|^2 + eps^2 only.
// Tabulate it (float-exponent/mantissa-indexed, 6 mantissa bits x 22 octaves,
// s in [2^-14, 2^8]), then symmetric all-pairs: acc[i] = sum_j m(s_ij)*(p_j-p_i).
// (j==i contributes exactly 0.)  Table stored in LDS as float2 (value, delta)
// so the interpolation gather is one ds_read_b64.

#define EPS2      1.0e-4f
#define TAB_BITS  6
#define TAB_SHIFT (23 - TAB_BITS)            // 17
#define TAB_EMIN  113                        // biased exponent of 2^-14
#define TAB_BASE  (TAB_EMIN << TAB_BITS)     // 7232
#define TAB_OCT   22                         // 2^-14 .. 2^8
#define TAB_N     (TAB_OCT << TAB_BITS)      // 1408 intervals, 1409 values

#define NPART   2048
#define BLOCK   512
#define CHUNK   512                          // i-particles per block
#define NSPLIT  64                           // j-range splits
#define JPT     (NPART / NSPLIT)             // 32 j per thread

// -------- table build (also zero-inits d_out; runs before forces) ----------
// 4 threads cooperate per entry (16 output-channels each), shfl-reduce.
__global__ void build_table(const float* __restrict__ W1, const float* __restrict__ b1,
                            const float* __restrict__ W2, const float* __restrict__ b2,
                            const float* __restrict__ W3, const float* __restrict__ b3,
                            float* __restrict__ tab, float* __restrict__ out, int out_n) {
    int t = blockIdx.x * blockDim.x + threadIdx.x;

    // zero d_out (harness poisons it to 0xAA before every launch)
    for (int k = t; k < out_n; k += gridDim.x * blockDim.x) out[k] = 0.0f;

    int entry = t >> 2;
    int og = t & 3;
    if (entry > TAB_N) return;

    unsigned u = (unsigned)(entry + TAB_BASE) << TAB_SHIFT;
    float s = __uint_as_float(u);            // exact sample point
    float d = sqrtf(s);
    float idc = 1.0f / (s * d);

    float h1[64];
#pragma unroll
    for (int k = 0; k < 64; ++k) {
        float v = fmaf(d, W1[k], fmaf(idc, W1[64 + k], b1[k]));
        h1[k] = v > 0.0f ? v : 0.0f;
    }

    float part = 0.0f;
#pragma unroll 2
    for (int oo = 0; oo < 16; ++oo) {
        int o = og * 16 + oo;
        float acc = b2[o];
#pragma unroll
        for (int k = 0; k < 64; ++k)
            acc = fmaf(h1[k], W2[k * 64 + o], acc);
        acc = acc > 0.0f ? acc : 0.0f;
        part = fmaf(acc, W3[o], part);
    }
    part += __shfl_down(part, 2, 4);
    part += __shfl_down(part, 1, 4);
    if (og == 0) tab[entry] = part + b3[0];
}

// ---------------- all-pairs force accumulation -----------------------------
__global__ __launch_bounds__(BLOCK, 6)
void forces(const float* __restrict__ pos, const float* __restrict__ tab,
            float* __restrict__ out) {
    __shared__ float2 tabs[TAB_N + 2];       // (value, next-value-delta): 11280 B
    __shared__ float4 ps[NPART];             // 32768 B   -> total ~44 KB, 3 blk/CU

    const int split = blockIdx.x;
    const int chunk = blockIdx.y;
    const int b     = blockIdx.z;

    const float* posb = pos + (size_t)b * NPART * 3;
    for (int k = threadIdx.x; k < TAB_N; k += BLOCK) {
        float t0 = tab[k], t1 = tab[k + 1];
        tabs[k] = make_float2(t0, t1 - t0);
    }
    for (int k = threadIdx.x; k < NPART; k += BLOCK)
        ps[k] = make_float4(posb[k * 3], posb[k * 3 + 1], posb[k * 3 + 2], 0.0f);
    __syncthreads();

    const int i = chunk * CHUNK + threadIdx.x;
    const float4 pi = ps[i];
    float ax = 0.0f, ay = 0.0f, az = 0.0f;

    const int j0 = split * JPT;
#pragma unroll 8
    for (int jj = 0; jj < JPT; ++jj) {
        float4 pj = ps[j0 + jj];             // wave-uniform -> LDS broadcast
        float dx = pj.x - pi.x;
        float dy = pj.y - pi.y;
        float dz = pj.z - pi.z;
        float s = fmaf(dx, dx, fmaf(dy, dy, fmaf(dz, dz, EPS2)));
        unsigned u = __float_as_uint(s);
        int idx = (int)(u >> TAB_SHIFT) - TAB_BASE;
        idx = idx < 0 ? 0 : (idx > TAB_N - 1 ? TAB_N - 1 : idx);
        float frac = (float)(u & ((1u << TAB_SHIFT) - 1)) * (1.0f / 131072.0f);
        float2 td = tabs[idx];               // one ds_read_b64 gather
        float m = fmaf(frac, td.y, td.x);
        ax = fmaf(m, dx, ax);
        ay = fmaf(m, dy, ay);
        az = fmaf(m, dz, az);
    }

    float* o = out + ((size_t)b * NPART + i) * 3;
    atomicAdd(o + 0, ax);
    atomicAdd(o + 1, ay);
    atomicAdd(o + 2, az);
}

extern "C" void kernel_launch(void* const* d_in, const int* in_sizes, int n_in,
                              void* d_out, int out_size, void* d_ws, size_t ws_size,
                              hipStream_t stream) {
    const float* pos = (const float*)d_in[0];
    const float* W1  = (const float*)d_in[1];
    const float* b1  = (const float*)d_in[2];
    const float* W2  = (const float*)d_in[3];
    const float* b2  = (const float*)d_in[4];
    const float* W3  = (const float*)d_in[5];
    const float* b3  = (const float*)d_in[6];
    float* out = (float*)d_out;
    float* tab = (float*)d_ws;               // (TAB_N+1) floats

    const int B = in_sizes[0] / (NPART * 3); // = 2

    int build_threads = (TAB_N + 1) * 4;     // 5636
    build_table<<<(build_threads + 255) / 256, 256, 0, stream>>>(
        W1, b1, W2, b2, W3, b3, tab, out, out_size);

    forces<<<dim3(NSPLIT, NPART / CHUNK, B), BLOCK, 0, stream>>>(pos, tab, out);
}

// Round 4
// 83.163 us; speedup vs baseline: 1.4098x; 1.3405x over previous
//
#include <hip/hip_runtime.h>

// m_ij = MLP([dist, dist^-3]) is a scalar function of s = |r|^2 + eps^2 only.
// Kernel 1 tabulates m(s) at float-bit sample points (6 mantissa bits x 22
// octaves, s in [2^-14, 2^8]) and zeroes d_out. Kernel 2 does symmetric
// all-pairs acc[i] = sum_j m(s_ij)*(p_j - p_i)  (j==i term is exactly 0),
// evaluating m via a per-interval (slope,intercept) LDS table: one
// ds_read_b64 gather + one fma per pair. p_j is wave-uniform -> scalar loads.

#define EPS2      1.0e-4f
#define TAB_BITS  6
#define TAB_SHIFT (23 - TAB_BITS)            // 17
#define TAB_EMIN  113                        // biased exponent of 2^-14
#define TAB_BASE  (TAB_EMIN << TAB_BITS)     // 7232
#define TAB_OCT   22                         // 2^-14 .. 2^8
#define TAB_N     (TAB_OCT << TAB_BITS)      // 1408 intervals

#define NPART  2048
#define BLOCK  512
#define CHUNK  512                           // i-particles per block
#define NSPLIT 64                            // j-range splits
#define JPT    (NPART / NSPLIT)              // 32 j per block's range

// ---- table build: 16 threads/entry, 4 contiguous outputs each ------------
// W2 accessed as float4 rows (o contiguous) -> global_load_dwordx4.
__global__ void build_table(const float* __restrict__ W1, const float* __restrict__ b1,
                            const float* __restrict__ W2, const float* __restrict__ b2,
                            const float* __restrict__ W3, const float* __restrict__ b3,
                            float* __restrict__ tab, float* __restrict__ out, int out_n) {
    const int t = blockIdx.x * blockDim.x + threadIdx.x;

    if (t < out_n) out[t] = 0.0f;            // harness poisons d_out to 0xAA

    const int entry = t >> 4;
    const int og    = t & 15;                // output group: 4 outputs each
    if (entry > TAB_N) return;

    const unsigned u = (unsigned)(entry + TAB_BASE) << TAB_SHIFT;
    const float s = __uint_as_float(u);      // exact sample point
    const float d = sqrtf(s);
    const float idc = 1.0f / (s * d);

    float4 acc = *(const float4*)(b2 + og * 4);
    const float* w2 = W2 + og * 4;
#pragma unroll
    for (int k = 0; k < 64; ++k) {
        float hv = fmaf(d, W1[k], fmaf(idc, W1[64 + k], b1[k]));
        hv = hv > 0.0f ? hv : 0.0f;
        float4 w = *(const float4*)(w2 + k * 64);
        acc.x = fmaf(hv, w.x, acc.x);
        acc.y = fmaf(hv, w.y, acc.y);
        acc.z = fmaf(hv, w.z, acc.z);
        acc.w = fmaf(hv, w.w, acc.w);
    }
    const float4 w3v = *(const float4*)(W3 + og * 4);
    float part = (acc.x > 0.0f ? acc.x : 0.0f) * w3v.x;
    part = fmaf(acc.y > 0.0f ? acc.y : 0.0f, w3v.y, part);
    part = fmaf(acc.z > 0.0f ? acc.z : 0.0f, w3v.z, part);
    part = fmaf(acc.w > 0.0f ? acc.w : 0.0f, w3v.w, part);

    part += __shfl_down(part, 8, 16);
    part += __shfl_down(part, 4, 16);
    part += __shfl_down(part, 2, 16);
    part += __shfl_down(part, 1, 16);
    if (og == 0) tab[entry] = part + b3[0];
}

// ---------------- all-pairs force accumulation -----------------------------
__global__ __launch_bounds__(BLOCK, 4)
void forces(const float* __restrict__ pos, const float* __restrict__ tab,
            float* __restrict__ out) {
    __shared__ float2 tabs[TAB_N + 1];       // (slope, intercept): 11272 B

    const int tid = threadIdx.x;

    // stage table as (a,b): m(s) = a*s + b on each interval. Interval width
    // is an exact power of 2 -> reciprocal by exponent arithmetic.
    for (int k = tid; k < TAB_N; k += BLOCK) {
        float t0 = tab[k], t1 = tab[k + 1];
        float s0 = __uint_as_float((unsigned)(k + TAB_BASE) << TAB_SHIFT);
        float rcpw = __uint_as_float((unsigned)(147 - (k >> TAB_BITS)) << 23);
        float a = (t1 - t0) * rcpw;
        tabs[k] = make_float2(a, fmaf(-a, s0, t0));
    }
    __syncthreads();

    const int split = blockIdx.x;
    const int chunk = blockIdx.y;
    const int b     = blockIdx.z;

    const float* posb = pos + (size_t)b * NPART * 3;
    const int i = chunk * CHUNK + tid;
    const float pix = posb[i * 3 + 0];
    const float piy = posb[i * 3 + 1];
    const float piz = posb[i * 3 + 2];

    float ax = 0.0f, ay = 0.0f, az = 0.0f;
    const float* pj = posb + split * JPT * 3;    // wave-uniform -> s_load

#pragma unroll 8
    for (int jj = 0; jj < JPT; ++jj) {
        float dx = pj[jj * 3 + 0] - pix;
        float dy = pj[jj * 3 + 1] - piy;
        float dz = pj[jj * 3 + 2] - piz;
        float s = fmaf(dx, dx, fmaf(dy, dy, fmaf(dz, dz, EPS2)));
        // s >= EPS2 = 1e-4 > 2^-14 so no underflow; unsigned min clamps high.
        unsigned idx = (__float_as_uint(s) >> TAB_SHIFT) - TAB_BASE;
        idx = idx > TAB_N - 1u ? TAB_N - 1u : idx;
        float2 ab = tabs[idx];                   // one ds_read_b64 gather
        float m = fmaf(s, ab.x, ab.y);
        ax = fmaf(m, dx, ax);
        ay = fmaf(m, dy, ay);
        az = fmaf(m, dz, az);
    }

    float* o = out + ((size_t)b * NPART + i) * 3;
    atomicAdd(o + 0, ax);
    atomicAdd(o + 1, ay);
    atomicAdd(o + 2, az);
}

extern "C" void kernel_launch(void* const* d_in, const int* in_sizes, int n_in,
                              void* d_out, int out_size, void* d_ws, size_t ws_size,
                              hipStream_t stream) {
    const float* pos = (const float*)d_in[0];
    const float* W1  = (const float*)d_in[1];
    const float* b1  = (const float*)d_in[2];
    const float* W2  = (const float*)d_in[3];
    const float* b2  = (const float*)d_in[4];
    const float* W3  = (const float*)d_in[5];
    const float* b3  = (const float*)d_in[6];
    float* out = (float*)d_out;
    float* tab = (float*)d_ws;               // (TAB_N+1) floats

    const int B = in_sizes[0] / (NPART * 3); // = 2

    const int build_threads = (TAB_N + 1) * 16;  // 22544 >= out_size (12288)
    build_table<<<(build_threads + 255) / 256, 256, 0, stream>>>(
        W1, b1, W2, b2, W3, b3, tab, out, out_size);

    forces<<<dim3(NSPLIT, NPART / CHUNK, B), BLOCK, 0, stream>>>(pos, tab, out);
}

// Round 5
// 78.718 us; speedup vs baseline: 1.4894x; 1.0565x over previous
//
#include <hip/hip_runtime.h>

// m_ij = MLP([dist, dist^-3]) is a scalar function of s = |r|^2 + eps^2 only.
// Kernel 1 tabulates m(s) at float-bit sample points (6 mantissa bits x 22
// octaves, s in [2^-14, 2^8]) and zeroes d_out. Kernel 2 does symmetric
// all-pairs acc[i] = sum_j m(s_ij)*(p_j - p_i)  (j==i term is exactly 0),
// evaluating m via a per-interval (slope,intercept) LDS table: one
// ds_read_b64 gather + one fma per pair. p_j is wave-uniform -> scalar loads.

#define EPS2      1.0e-4f
#define TAB_BITS  6
#define TAB_SHIFT (23 - TAB_BITS)            // 17
#define TAB_EMIN  113                        // biased exponent of 2^-14
#define TAB_BASE  (TAB_EMIN << TAB_BITS)     // 7232
#define TAB_OCT   22                         // 2^-14 .. 2^8
#define TAB_N     (TAB_OCT << TAB_BITS)      // 1408 intervals

#define NPART  2048
#define BLOCK  512
#define CHUNK  512                           // i-particles per block
#define NSPLIT 32                            // j-range splits (256 blocks = 1/CU)
#define JPT    (NPART / NSPLIT)              // 64 j per block's range

// ---- table build: 64 threads/entry, one output channel per lane ----------
// W2[k*64 + lane] is a coalesced 256B/wave load; W1/b1 are wave-uniform.
__global__ void build_table(const float* __restrict__ W1, const float* __restrict__ b1,
                            const float* __restrict__ W2, const float* __restrict__ b2,
                            const float* __restrict__ W3, const float* __restrict__ b3,
                            float* __restrict__ tab, float* __restrict__ out, int out_n) {
    const int t = blockIdx.x * blockDim.x + threadIdx.x;

    if (t < out_n) out[t] = 0.0f;            // harness poisons d_out to 0xAA

    const int entry = t >> 6;
    const int o     = t & 63;                // output channel == lane
    if (entry > TAB_N) return;

    const unsigned u = (unsigned)(entry + TAB_BASE) << TAB_SHIFT;
    const float s = __uint_as_float(u);      // exact sample point
    const float d = sqrtf(s);
    const float idc = 1.0f / (s * d);

    float acc = b2[o];
#pragma unroll
    for (int k = 0; k < 64; ++k) {
        float hv = fmaf(d, W1[k], fmaf(idc, W1[64 + k], b1[k]));
        hv = hv > 0.0f ? hv : 0.0f;
        acc = fmaf(hv, W2[k * 64 + o], acc);
    }
    float part = (acc > 0.0f ? acc : 0.0f) * W3[o];

    part += __shfl_down(part, 32, 64);
    part += __shfl_down(part, 16, 64);
    part += __shfl_down(part, 8, 64);
    part += __shfl_down(part, 4, 64);
    part += __shfl_down(part, 2, 64);
    part += __shfl_down(part, 1, 64);
    if (o == 0) tab[entry] = part + b3[0];
}

// ---------------- all-pairs force accumulation -----------------------------
__global__ __launch_bounds__(BLOCK, 4)
void forces(const float* __restrict__ pos, const float* __restrict__ tab,
            float* __restrict__ out) {
    __shared__ float2 tabs[TAB_N + 1];       // (slope, intercept): 11272 B

    const int tid = threadIdx.x;

    // stage table as (a,b): m(s) = a*s + b on each interval. Interval width
    // is an exact power of 2 -> reciprocal by exponent arithmetic.
    for (int k = tid; k < TAB_N; k += BLOCK) {
        float t0 = tab[k], t1 = tab[k + 1];
        float s0 = __uint_as_float((unsigned)(k + TAB_BASE) << TAB_SHIFT);
        float rcpw = __uint_as_float((unsigned)(147 - (k >> TAB_BITS)) << 23);
        float a = (t1 - t0) * rcpw;
        tabs[k] = make_float2(a, fmaf(-a, s0, t0));
    }
    __syncthreads();

    const int split = blockIdx.x;
    const int chunk = blockIdx.y;
    const int b     = blockIdx.z;

    const float* posb = pos + (size_t)b * NPART * 3;
    const int i = chunk * CHUNK + tid;
    const float pix = posb[i * 3 + 0];
    const float piy = posb[i * 3 + 1];
    const float piz = posb[i * 3 + 2];

    float ax = 0.0f, ay = 0.0f, az = 0.0f;
    const float* pj = posb + split * JPT * 3;    // wave-uniform -> s_load

#pragma unroll 8
    for (int jj = 0; jj < JPT; ++jj) {
        float dx = pj[jj * 3 + 0] - pix;
        float dy = pj[jj * 3 + 1] - piy;
        float dz = pj[jj * 3 + 2] - piz;
        float s = fmaf(dx, dx, fmaf(dy, dy, fmaf(dz, dz, EPS2)));
        // s >= EPS2 = 1e-4 > 2^-14 so no underflow; unsigned min clamps high.
        unsigned idx = (__float_as_uint(s) >> TAB_SHIFT) - TAB_BASE;
        idx = idx > TAB_N - 1u ? TAB_N - 1u : idx;
        float2 ab = tabs[idx];                   // one ds_read_b64 gather
        float m = fmaf(s, ab.x, ab.y);
        ax = fmaf(m, dx, ax);
        ay = fmaf(m, dy, ay);
        az = fmaf(m, dz, az);
    }

    float* o = out + ((size_t)b * NPART + i) * 3;
    atomicAdd(o + 0, ax);
    atomicAdd(o + 1, ay);
    atomicAdd(o + 2, az);
}

extern "C" void kernel_launch(void* const* d_in, const int* in_sizes, int n_in,
                              void* d_out, int out_size, void* d_ws, size_t ws_size,
                              hipStream_t stream) {
    const float* pos = (const float*)d_in[0];
    const float* W1  = (const float*)d_in[1];
    const float* b1  = (const float*)d_in[2];
    const float* W2  = (const float*)d_in[3];
    const float* b2  = (const float*)d_in[4];
    const float* W3  = (const float*)d_in[5];
    const float* b3  = (const float*)d_in[6];
    float* out = (float*)d_out;
    float* tab = (float*)d_ws;               // (TAB_N+1) floats

    const int B = in_sizes[0] / (NPART * 3); // = 2

    const int build_threads = (TAB_N + 1) * 64;  // 90176 >= out_size (12288)
    build_table<<<(build_threads + 255) / 256, 256, 0, stream>>>(
        W1, b1, W2, b2, W3, b3, tab, out, out_size);

    forces<<<dim3(NSPLIT, NPART / CHUNK, B), BLOCK, 0, stream>>>(pos, tab, out);
}